// Round 1
// baseline (5966.617 us; speedup 1.0000x reference)
//
#include <hip/hip_runtime.h>
#include <cmath>

#define C_   128
#define H_   256
#define W_   256
#define HW_  65536
#define B_   8
#define NH_  4
#define DH_  32
#define WS_  8
#define WIN_ 64

// Kernel 1: per-(b,c) mean and rstd over the 65536 spatial elements.
__global__ __launch_bounds__(256) void ln_stats_kernel(const float* __restrict__ x,
                                                       float* __restrict__ stats) {
  const int bc = blockIdx.x;                      // 0..1023
  const float4* p4 = (const float4*)(x + (size_t)bc * HW_);
  float s = 0.f, ss = 0.f;
  for (int idx = threadIdx.x; idx < HW_ / 4; idx += 256) {
    float4 v = p4[idx];
    s  += (v.x + v.y) + (v.z + v.w);
    ss += (v.x * v.x + v.y * v.y) + (v.z * v.z + v.w * v.w);
  }
  #pragma unroll
  for (int off = 32; off > 0; off >>= 1) {
    s  += __shfl_down(s, off, 64);
    ss += __shfl_down(ss, off, 64);
  }
  __shared__ float red[8];
  const int wv = threadIdx.x >> 6;
  if ((threadIdx.x & 63) == 0) { red[wv * 2] = s; red[wv * 2 + 1] = ss; }
  __syncthreads();
  if (threadIdx.x == 0) {
    float S = 0.f, SS = 0.f;
    #pragma unroll
    for (int w = 0; w < 4; ++w) { S += red[w * 2]; SS += red[w * 2 + 1]; }
    const float mean = S * (1.f / HW_);
    const float var  = SS * (1.f / HW_) - mean * mean;
    stats[bc * 2]     = mean;
    stats[bc * 2 + 1] = rsqrtf(var + 1e-6f);
  }
}

// Kernel 2: one block per 8x8 window. Thread (h = tid>>6, i = tid&63) owns
// token i of head h. Fuses LN-apply + QKV + attention + proj.
__global__ __launch_bounds__(256, 2) void win_attn_kernel(
    const float* __restrict__ x, const float* __restrict__ stats,
    const float* __restrict__ norm_w, const float* __restrict__ norm_b,
    const float* __restrict__ qkv_w, const float* __restrict__ qkv_b,
    const float* __restrict__ proj_w, const float* __restrict__ proj_b,
    float* __restrict__ out)
{
  // ldsA: K as [head*64+token][d] (32 KB), then attn-out as [c][token] (32 KB)
  // ldsB: V as [head*64+token][d] (32 KB)
  __shared__ float ldsA[NH_ * WIN_ * DH_];
  __shared__ float ldsB[NH_ * WIN_ * DH_];

  const int tid = threadIdx.x;
  const int i   = tid & 63;
  const int h   = __builtin_amdgcn_readfirstlane(tid >> 6);  // wave-uniform head
  const int ww  = blockIdx.x, wh = blockIdx.y, b = blockIdx.z;

  const size_t pix = (size_t)(wh * WS_ + (i >> 3)) * W_ + (size_t)(ww * WS_ + (i & 7));
  const float* xb   = x   + (size_t)b * C_ * HW_ + pix;
  float*       outb = out + (size_t)b * C_ * HW_ + pix;
  const float* st   = stats + b * C_ * 2;

  // ---- QKV rows for this (head, token) in registers ----
  alignas(16) float q[DH_], k[DH_], v[DH_];
  #pragma unroll
  for (int d = 0; d < DH_; ++d) {
    q[d] = qkv_b[h * DH_ + d];
    k[d] = qkv_b[C_ + h * DH_ + d];
    v[d] = qkv_b[2 * C_ + h * DH_ + d];
  }

  for (int cb = 0; cb < C_; cb += 32) {      // channel chunks of 32
    float xcol[32];
    #pragma unroll
    for (int c = 0; c < 32; ++c) {
      const int gc = cb + c;
      const float xv = xb[(size_t)gc * HW_];
      xcol[c] = (xv - st[gc * 2]) * st[gc * 2 + 1] * norm_w[gc] + norm_b[gc];
    }
    #pragma unroll
    for (int d = 0; d < DH_; ++d) {
      const float* wq = qkv_w + (h * DH_ + d) * C_ + cb;     // wave-uniform rows
      const float* wk = wq + C_ * C_;
      const float* wvp = wq + 2 * C_ * C_;
      float aq = 0.f, ak = 0.f, av = 0.f;
      #pragma unroll
      for (int c = 0; c < 32; ++c) {
        aq = fmaf(wq[c],  xcol[c], aq);
        ak = fmaf(wk[c],  xcol[c], ak);
        av = fmaf(wvp[c], xcol[c], av);
      }
      q[d] += aq; k[d] += ak; v[d] += av;
    }
  }

  // ---- stage K, V to LDS ----
  {
    float4* kd = (float4*)&ldsA[(h * WIN_ + i) * DH_];
    float4* vd = (float4*)&ldsB[(h * WIN_ + i) * DH_];
    #pragma unroll
    for (int d4 = 0; d4 < DH_ / 4; ++d4) {
      kd[d4] = *(const float4*)&k[d4 * 4];
      vd[d4] = *(const float4*)&v[d4 * 4];
    }
  }
  __syncthreads();

  // ---- scores S[i][j] = scale * q_i . k_j  (broadcast LDS reads) ----
  const float scale = 0.17677669529663687f;   // 32^-0.5
  float S[WIN_];
  #pragma unroll
  for (int j = 0; j < WIN_; ++j) {
    const float4* kr = (const float4*)&ldsA[(h * WIN_ + j) * DH_];
    float acc = 0.f;
    #pragma unroll
    for (int d4 = 0; d4 < DH_ / 4; ++d4) {
      const float4 kv = kr[d4];
      acc += q[d4 * 4 + 0] * kv.x + q[d4 * 4 + 1] * kv.y
           + q[d4 * 4 + 2] * kv.z + q[d4 * 4 + 3] * kv.w;
    }
    S[j] = acc * scale;
  }

  // ---- softmax over j ----
  float m = S[0];
  #pragma unroll
  for (int j = 1; j < WIN_; ++j) m = fmaxf(m, S[j]);
  float sum = 0.f;
  #pragma unroll
  for (int j = 0; j < WIN_; ++j) { S[j] = __expf(S[j] - m); sum += S[j]; }
  const float inv = 1.f / sum;

  __syncthreads();   // all K reads done -> ldsA reusable for attn-out

  // ---- out_i = sum_j P[i][j] * v_j ----
  float o_[DH_];
  #pragma unroll
  for (int d = 0; d < DH_; ++d) o_[d] = 0.f;
  #pragma unroll
  for (int j = 0; j < WIN_; ++j) {
    const float4* vr = (const float4*)&ldsB[(h * WIN_ + j) * DH_];
    const float p = S[j];
    #pragma unroll
    for (int d4 = 0; d4 < DH_ / 4; ++d4) {
      const float4 vv = vr[d4];
      o_[d4 * 4 + 0] = fmaf(p, vv.x, o_[d4 * 4 + 0]);
      o_[d4 * 4 + 1] = fmaf(p, vv.y, o_[d4 * 4 + 1]);
      o_[d4 * 4 + 2] = fmaf(p, vv.z, o_[d4 * 4 + 2]);
      o_[d4 * 4 + 3] = fmaf(p, vv.w, o_[d4 * 4 + 3]);
    }
  }

  // ---- write attn-out as [c][token] for proj ----
  #pragma unroll
  for (int d = 0; d < DH_; ++d) ldsA[(h * DH_ + d) * WIN_ + i] = o_[d] * inv;
  __syncthreads();

  // ---- proj: thread computes 32 output channels o = j*4 + h at token i ----
  float acc[32];
  #pragma unroll
  for (int j = 0; j < 32; ++j) acc[j] = proj_b[j * NH_ + h];
  for (int cb = 0; cb < C_; cb += 32) {
    float xcol[32];
    #pragma unroll
    for (int c = 0; c < 32; ++c) xcol[c] = ldsA[(cb + c) * WIN_ + i];
    #pragma unroll
    for (int j = 0; j < 32; ++j) {
      const float* wp = proj_w + (j * NH_ + h) * C_ + cb;    // wave-uniform row
      float a = 0.f;
      #pragma unroll
      for (int c = 0; c < 32; ++c) a = fmaf(wp[c], xcol[c], a);
      acc[j] += a;
    }
  }
  #pragma unroll
  for (int j = 0; j < 32; ++j) outb[(size_t)(j * NH_ + h) * HW_] = acc[j];
}

extern "C" void kernel_launch(void* const* d_in, const int* in_sizes, int n_in,
                              void* d_out, int out_size, void* d_ws, size_t ws_size,
                              hipStream_t stream) {
  const float* x      = (const float*)d_in[0];
  const float* norm_w = (const float*)d_in[1];
  const float* norm_b = (const float*)d_in[2];
  const float* qkv_w  = (const float*)d_in[3];
  const float* qkv_b  = (const float*)d_in[4];
  const float* proj_w = (const float*)d_in[5];
  const float* proj_b = (const float*)d_in[6];
  float* out   = (float*)d_out;
  float* stats = (float*)d_ws;    // 1024 * 2 floats

  hipLaunchKernelGGL(ln_stats_kernel, dim3(B_ * C_), dim3(256), 0, stream, x, stats);
  hipLaunchKernelGGL(win_attn_kernel, dim3(W_ / WS_, H_ / WS_, B_), dim3(256), 0, stream,
                     x, stats, norm_w, norm_b, qkv_w, qkv_b, proj_w, proj_b, out);
}

// Round 2
// 831.323 us; speedup vs baseline: 7.1773x; 7.1773x over previous
//
#include <hip/hip_runtime.h>
#include <hip/hip_bf16.h>

#define C_    128
#define HW_   65536
#define B_    8
#define WIMG_ 256

typedef __attribute__((ext_vector_type(8))) short short8;
typedef __attribute__((ext_vector_type(4))) float floatx4;

static __device__ __forceinline__ short f2bf(float x) {
  __hip_bfloat16 h = __float2bfloat16(x);
  return *reinterpret_cast<short*>(&h);
}
static __device__ __forceinline__ int pack2(float a, float b) {
  return (int)(unsigned short)f2bf(a) | ((int)(unsigned short)f2bf(b) << 16);
}

// ---- Kernel 1: per-(b,c) mean/rstd over 65536 spatial elems ----
__global__ __launch_bounds__(1024) void ln_stats_kernel(const float* __restrict__ x,
                                                        float* __restrict__ stats) {
  const int bc = blockIdx.x;
  const float4* p4 = (const float4*)(x + (size_t)bc * HW_);
  float s = 0.f, ss = 0.f;
  for (int i = threadIdx.x; i < HW_ / 4; i += 1024) {
    float4 v = p4[i];
    s  += (v.x + v.y) + (v.z + v.w);
    ss += (v.x * v.x + v.y * v.y) + (v.z * v.z + v.w * v.w);
  }
  #pragma unroll
  for (int off = 32; off > 0; off >>= 1) {
    s  += __shfl_down(s, off, 64);
    ss += __shfl_down(ss, off, 64);
  }
  __shared__ float red[32];
  const int wv = threadIdx.x >> 6;
  if ((threadIdx.x & 63) == 0) { red[wv * 2] = s; red[wv * 2 + 1] = ss; }
  __syncthreads();
  if (threadIdx.x == 0) {
    float S = 0.f, SS = 0.f;
    #pragma unroll
    for (int v = 0; v < 16; ++v) { S += red[v * 2]; SS += red[v * 2 + 1]; }
    const float mean = S * (1.f / HW_);
    const float var  = SS * (1.f / HW_) - mean * mean;
    stats[bc * 2]     = mean;
    stats[bc * 2 + 1] = rsqrtf(var + 1e-6f);
  }
}

// ---- Kernel 2: fp32 -> bf16 weight conversion into workspace ----
__global__ __launch_bounds__(256) void cvt_w_kernel(const float* __restrict__ qkv_w,
                                                    const float* __restrict__ proj_w,
                                                    short* __restrict__ dst) {
  const int i = blockIdx.x * 256 + threadIdx.x;        // 0..65535
  const float v = (i < 49152) ? qkv_w[i] : proj_w[i - 49152];
  dst[i] = f2bf(v);
}

// ---- Kernel 3: fused LN-apply + QKV + window attention + proj, MFMA ----
// One block per 8x8 window; wave w = head h. LDS regions (bytes):
//   Xn [64][136] bf16 @0      (17408)   normalized input, token-major
//   Qr [64][136] bf16 @17408  (17408)   Q token-major (cols 0..127 = h*32+d)
//   Kr [64][136] bf16 @34816  (17408)
//   Vr [128][72] bf16 @52224  (18432)   V d-major
//   P  (per wave) [64][72] bf16 @ w*9216  — overlaps Xn+Qr+head of Kr (dead)
//   Att [64][136] bf16 @34816 — overlaps Kr (dead after scores)
__global__ __launch_bounds__(256, 2) void win_attn_kernel(
    const float* __restrict__ x, const float* __restrict__ stats,
    const float* __restrict__ norm_w, const float* __restrict__ norm_b,
    const short* __restrict__ wq, const float* __restrict__ qkv_b,
    const short* __restrict__ wp, const float* __restrict__ proj_b,
    float* __restrict__ out)
{
  __shared__ __align__(16) char lds[70656];
  short* Xn = (short*)lds;
  short* Qr = (short*)(lds + 17408);
  short* Kr = (short*)(lds + 34816);
  short* Vr = (short*)(lds + 52224);

  const int tid = threadIdx.x;
  const int l15 = tid & 15;
  const int qd  = (tid >> 4) & 3;           // quad within wave
  const int w   = tid >> 6;                 // wave = head
  const int ww = blockIdx.x, wh = blockIdx.y, b = blockIdx.z;

  const float* xb = x + (size_t)b * C_ * HW_ + (size_t)(wh * 8) * WIMG_ + ww * 8;
  const float* st = stats + b * C_ * 2;

  // ---- Phase A: stage normalized window as bf16 Xn[t][c] ----
  {
    const int c = tid >> 1, half = tid & 1;
    const float aa = st[c * 2 + 1] * norm_w[c];
    const float bb = norm_b[c] - st[c * 2] * aa;
    const float* xc = xb + (size_t)c * HW_ + half * 4;
    #pragma unroll
    for (int r = 0; r < 8; ++r) {
      float4 v = *(const float4*)(xc + r * WIMG_);
      const int t = r * 8 + half * 4;
      Xn[(t + 0) * 136 + c] = f2bf(v.x * aa + bb);
      Xn[(t + 1) * 136 + c] = f2bf(v.y * aa + bb);
      Xn[(t + 2) * 136 + c] = f2bf(v.z * aa + bb);
      Xn[(t + 3) * 136 + c] = f2bf(v.w * aa + bb);
    }
  }
  __syncthreads();

  // ---- Phase B: QKV GEMM, wave w computes output rows [w*96, w*96+96) ----
  const float scale = 0.17677669529663687f;   // 32^-0.5, folded into Q
  {
    floatx4 acc[6][4];
    const int ro = w * 96;
    #pragma unroll
    for (int mt = 0; mt < 6; ++mt)
      #pragma unroll
      for (int r = 0; r < 4; ++r) {
        const float bias = qkv_b[ro + mt * 16 + qd * 4 + r];
        #pragma unroll
        for (int nt = 0; nt < 4; ++nt) acc[mt][nt][r] = bias;
      }
    #pragma unroll
    for (int kb = 0; kb < 4; ++kb) {
      short8 bfr[4];
      #pragma unroll
      for (int nt = 0; nt < 4; ++nt)
        bfr[nt] = *(const short8*)&Xn[(nt * 16 + l15) * 136 + kb * 32 + qd * 8];
      #pragma unroll
      for (int mt = 0; mt < 6; ++mt) {
        short8 af = *(const short8*)&wq[(ro + mt * 16 + l15) * 128 + kb * 32 + qd * 8];
        #pragma unroll
        for (int nt = 0; nt < 4; ++nt)
          acc[mt][nt] = __builtin_amdgcn_mfma_f32_16x16x32_bf16(af, bfr[nt], acc[mt][nt], 0, 0, 0);
      }
    }
    // scatter QKV to LDS (Q scaled; Q/K token-major packed b32 writes, V d-major)
    #pragma unroll
    for (int mt = 0; mt < 6; ++mt) {
      const int ob = ro + mt * 16;            // wave-uniform
      #pragma unroll
      for (int nt = 0; nt < 4; ++nt) {
        const int t = nt * 16 + l15;
        floatx4 a = acc[mt][nt];
        if (ob < 128) {
          const int ol = ob + qd * 4;
          *(int*)&Qr[t * 136 + ol]     = pack2(a[0] * scale, a[1] * scale);
          *(int*)&Qr[t * 136 + ol + 2] = pack2(a[2] * scale, a[3] * scale);
        } else if (ob < 256) {
          const int ol = (ob - 128) + qd * 4;
          *(int*)&Kr[t * 136 + ol]     = pack2(a[0], a[1]);
          *(int*)&Kr[t * 136 + ol + 2] = pack2(a[2], a[3]);
        } else {
          const int o0 = (ob - 256) + qd * 4;
          #pragma unroll
          for (int r = 0; r < 4; ++r) Vr[(o0 + r) * 72 + t] = f2bf(a[r]);
        }
      }
    }
  }
  __syncthreads();

  // ---- Phase C: scores S = (Q*scale)^T K + softmax (head h = w) ----
  const int h = w;
  floatx4 s[4][4];
  {
    short8 qa[4], ka[4];
    #pragma unroll
    for (int it = 0; it < 4; ++it)
      qa[it] = *(const short8*)&Qr[(it * 16 + l15) * 136 + h * 32 + qd * 8];
    #pragma unroll
    for (int jt = 0; jt < 4; ++jt)
      ka[jt] = *(const short8*)&Kr[(jt * 16 + l15) * 136 + h * 32 + qd * 8];
    const floatx4 z = {0.f, 0.f, 0.f, 0.f};
    #pragma unroll
    for (int it = 0; it < 4; ++it)
      #pragma unroll
      for (int jt = 0; jt < 4; ++jt)
        s[it][jt] = __builtin_amdgcn_mfma_f32_16x16x32_bf16(qa[it], ka[jt], z, 0, 0, 0);
  }
  float rs[4][4];                              // 1/rowsum, rows match PV C-layout
  #pragma unroll
  for (int it = 0; it < 4; ++it)
    #pragma unroll
    for (int r = 0; r < 4; ++r) {
      float m = fmaxf(fmaxf(s[it][0][r], s[it][1][r]), fmaxf(s[it][2][r], s[it][3][r]));
      m = fmaxf(m, __shfl_xor(m, 1)); m = fmaxf(m, __shfl_xor(m, 2));
      m = fmaxf(m, __shfl_xor(m, 4)); m = fmaxf(m, __shfl_xor(m, 8));
      float sm = 0.f;
      #pragma unroll
      for (int jt = 0; jt < 4; ++jt) { s[it][jt][r] = __expf(s[it][jt][r] - m); sm += s[it][jt][r]; }
      sm += __shfl_xor(sm, 1); sm += __shfl_xor(sm, 2);
      sm += __shfl_xor(sm, 4); sm += __shfl_xor(sm, 8);
      rs[it][r] = 1.f / sm;
    }
  __syncthreads();                             // Q/K/Xn dead everywhere

  // ---- write P (unnormalized exp) to per-wave LDS [64][72] ----
  short* Pw = (short*)(lds + w * 9216);
  #pragma unroll
  for (int it = 0; it < 4; ++it)
    #pragma unroll
    for (int jt = 0; jt < 4; ++jt)
      #pragma unroll
      for (int r = 0; r < 4; ++r)
        Pw[(it * 16 + qd * 4 + r) * 72 + jt * 16 + l15] = f2bf(s[it][jt][r]);
  __syncthreads();

  // ---- Phase D: O = P V (normalization folded into epilogue) ----
  floatx4 o[4][2];
  #pragma unroll
  for (int it = 0; it < 4; ++it)
    #pragma unroll
    for (int dt = 0; dt < 2; ++dt) o[it][dt] = (floatx4){0.f, 0.f, 0.f, 0.f};
  #pragma unroll
  for (int kb = 0; kb < 2; ++kb) {
    short8 pa[4], vb[2];
    #pragma unroll
    for (int it = 0; it < 4; ++it)
      pa[it] = *(const short8*)&Pw[(it * 16 + l15) * 72 + kb * 32 + qd * 8];
    #pragma unroll
    for (int dt = 0; dt < 2; ++dt)
      vb[dt] = *(const short8*)&Vr[(h * 32 + dt * 16 + l15) * 72 + kb * 32 + qd * 8];
    #pragma unroll
    for (int it = 0; it < 4; ++it)
      #pragma unroll
      for (int dt = 0; dt < 2; ++dt)
        o[it][dt] = __builtin_amdgcn_mfma_f32_16x16x32_bf16(pa[it], vb[dt], o[it][dt], 0, 0, 0);
  }
  __syncthreads();                             // all P reads done -> Kr region reusable

  // ---- Att[t][c] bf16 for proj (channel c = h*32+d) ----
  short* Att = (short*)(lds + 34816);
  #pragma unroll
  for (int it = 0; it < 4; ++it)
    #pragma unroll
    for (int dt = 0; dt < 2; ++dt)
      #pragma unroll
      for (int r = 0; r < 4; ++r)
        Att[(it * 16 + qd * 4 + r) * 136 + h * 32 + dt * 16 + l15] = f2bf(o[it][dt][r] * rs[it][r]);
  __syncthreads();

  // ---- Phase E: proj GEMM, wave w computes output channels [w*32, w*32+32) ----
  {
    floatx4 pacc[2][4];
    #pragma unroll
    for (int mt = 0; mt < 2; ++mt)
      #pragma unroll
      for (int r = 0; r < 4; ++r) {
        const float bias = proj_b[w * 32 + mt * 16 + qd * 4 + r];
        #pragma unroll
        for (int nt = 0; nt < 4; ++nt) pacc[mt][nt][r] = bias;
      }
    #pragma unroll
    for (int kb = 0; kb < 4; ++kb) {
      short8 bfr[4];
      #pragma unroll
      for (int nt = 0; nt < 4; ++nt)
        bfr[nt] = *(const short8*)&Att[(nt * 16 + l15) * 136 + kb * 32 + qd * 8];
      #pragma unroll
      for (int mt = 0; mt < 2; ++mt) {
        short8 af = *(const short8*)&wp[(w * 32 + mt * 16 + l15) * 128 + kb * 32 + qd * 8];
        #pragma unroll
        for (int nt = 0; nt < 4; ++nt)
          pacc[mt][nt] = __builtin_amdgcn_mfma_f32_16x16x32_bf16(af, bfr[nt], pacc[mt][nt], 0, 0, 0);
      }
    }
    float* ob_ = out + (size_t)b * C_ * HW_ + (size_t)(wh * 8) * WIMG_ + ww * 8;
    #pragma unroll
    for (int mt = 0; mt < 2; ++mt)
      #pragma unroll
      for (int nt = 0; nt < 4; ++nt)
        #pragma unroll
        for (int r = 0; r < 4; ++r) {
          const int oc = w * 32 + mt * 16 + qd * 4 + r;
          const int t  = nt * 16 + l15;
          ob_[(size_t)oc * HW_ + (t >> 3) * WIMG_ + (t & 7)] = pacc[mt][nt][r];
        }
  }
}

extern "C" void kernel_launch(void* const* d_in, const int* in_sizes, int n_in,
                              void* d_out, int out_size, void* d_ws, size_t ws_size,
                              hipStream_t stream) {
  const float* x      = (const float*)d_in[0];
  const float* norm_w = (const float*)d_in[1];
  const float* norm_b = (const float*)d_in[2];
  const float* qkv_w  = (const float*)d_in[3];
  const float* qkv_b  = (const float*)d_in[4];
  const float* proj_w = (const float*)d_in[5];
  const float* proj_b = (const float*)d_in[6];
  float* out   = (float*)d_out;
  float* stats = (float*)d_ws;                         // 1024*2 f32 = 8 KB
  short* wq    = (short*)((char*)d_ws + 8192);         // 384*128 bf16
  short* wp    = wq + 384 * 128;                       // 128*128 bf16

  hipLaunchKernelGGL(cvt_w_kernel, dim3(256), dim3(256), 0, stream, qkv_w, proj_w, wq);
  hipLaunchKernelGGL(ln_stats_kernel, dim3(B_ * C_), dim3(1024), 0, stream, x, stats);
  hipLaunchKernelGGL(win_attn_kernel, dim3(32, 32, B_), dim3(256), 0, stream,
                     x, stats, norm_w, norm_b, wq, qkv_b, wp, proj_b, out);
}